// Round 5
// baseline (189.975 us; speedup 1.0000x reference)
//
#include <hip/hip_runtime.h>
#include <math.h>

#define B_ROWS 2048
#define P_ROWS 100000
#define D_DIM  128
#define NPC    64                 // pool chunks (grid.x of gemm)
#define NT     782                // 128-row pool tiles
#define TILEB  32768              // 128 pool-rows x 128 bf16 (256 B/row)
#define NCAND  (NPC * 3)          // 192 screened candidates (pairs) per row

typedef short short8 __attribute__((ext_vector_type(8)));
typedef float f32x4  __attribute__((ext_vector_type(4)));
typedef unsigned long long u64;

// bf16 RNE
__device__ __forceinline__ unsigned short f2bf(float f) {
    unsigned u = __float_as_uint(f);
    u += 0x7fffu + ((u >> 16) & 1u);
    return (unsigned short)(u >> 16);
}

__device__ __forceinline__ void async16(const char* g, char* l) {
    __builtin_amdgcn_global_load_lds(
        (const __attribute__((address_space(1))) unsigned int*)g,
        (__attribute__((address_space(3))) unsigned int*)l,
        16, 0, 0);
}

// u64 branchless top-3 insert
__device__ __forceinline__ void kins64(u64 k, u64& t0, u64& t1, u64& t2) {
    u64 m0 = (t0 < k) ? t0 : k;  t0 = (t0 < k) ? k : t0;
    u64 m1 = (t1 < m0) ? t1 : m0; t1 = (t1 < m0) ? m0 : t1;
    t2 = (t2 < m1) ? m1 : t2;
}

// fp64 top-3 insert with index tie-break (lower index wins)
__device__ __forceinline__ void ins3d(double v, int c,
                                      double& v0, int& i0,
                                      double& v1, int& i1,
                                      double& v2, int& i2) {
    bool b0 = (v > v0) || (v == v0 && c < i0);
    bool b1 = (v > v1) || (v == v1 && c < i1);
    bool b2 = (v > v2) || (v == v2 && c < i2);
    if (b0)      { v2 = v1; i2 = i1; v1 = v0; i1 = i0; v0 = v; i0 = c; }
    else if (b1) { v2 = v1; i2 = i1; v1 = v;  i1 = c; }
    else if (b2) { v2 = v;  i2 = c; }
}

// ---------------------------------------------------------------------------
// Kernel 1 (R15 merged): blocks [0,NT) pack pool; blocks [NT,NT+512) pack
// sess. Pool path is SINGLE-PASS: row norm via 4-step shfl_xor inside the
// 16-lane row group. One barrier at the end for the per-block S partial.
// ---------------------------------------------------------------------------
__global__ void pack_kernel(const float* __restrict__ sess,
                            const float* __restrict__ pool,
                            char* __restrict__ sess2,
                            char* __restrict__ pool2,
                            float* __restrict__ S_part) {
    const int tid = threadIdx.x;
    const int bx  = blockIdx.x;

    if (bx >= NT) {               // ---- sess path: one wave per row ----
        int row  = (bx - NT) * 4 + (tid >> 6);
        int lane = tid & 63;
        float2 v = ((const float2*)(sess + (size_t)row * D_DIM))[lane];
        float s = v.x * v.x + v.y * v.y;
        #pragma unroll
        for (int o = 32; o > 0; o >>= 1) s += __shfl_xor(s, o);
        float inv = 1.0f / sqrtf(s + (float)D_DIM * 1e-6f);
        ushort2 hv;
        hv.x = f2bf(v.x * inv);
        hv.y = f2bf(v.y * inv);
        *(ushort2*)(sess2 + (size_t)row * 256 + lane * 4) = hv;
        return;
    }

    // ---- pool path ----
    __shared__ float red2[16][128];
    const int T  = bx;
    const int c0 = tid >> 4;      // row-in-iteration (16 rows/iter)
    const int g  = tid & 15;      // 8-elem group within the row

    float sacc[8] = {0.f,0.f,0.f,0.f,0.f,0.f,0.f,0.f};
    #pragma unroll
    for (int it = 0; it < 8; ++it) {
        int c = it * 16 + c0;
        int n = T * 128 + c;
        float4 a = make_float4(0.f, 0.f, 0.f, 0.f), b = a;
        if (n < P_ROWS) {
            const float4* src = (const float4*)(pool + (size_t)n * D_DIM + g * 8);
            a = src[0]; b = src[1];
        }
        float s = a.x*a.x + a.y*a.y + a.z*a.z + a.w*a.w
                + b.x*b.x + b.y*b.y + b.z*b.z + b.w*b.w;
        // row-sum across the 16 lanes owning row c (aligned 16-lane group)
        s += __shfl_xor(s, 1);
        s += __shfl_xor(s, 2);
        s += __shfl_xor(s, 4);
        s += __shfl_xor(s, 8);
        float inv = 1.0f / sqrtf(s + (float)D_DIM * 1e-6f);
        const float f[8] = {a.x, a.y, a.z, a.w, b.x, b.y, b.z, b.w};
        short8 hv;
        #pragma unroll
        for (int j = 0; j < 8; ++j) {
            float w = f[j] * inv;
            hv[j] = (short)f2bf(w);
            sacc[j] += w;
        }
        *(short8*)(pool2 + (size_t)T * TILEB + c * 256 + ((g ^ (c & 7)) * 16)) = hv;
    }
    #pragma unroll
    for (int j = 0; j < 8; ++j) red2[c0][g * 8 + j] = sacc[j];
    __syncthreads();
    if (tid < 128) {
        float s = 0.f;
        #pragma unroll
        for (int k = 0; k < 16; ++k) s += red2[k][tid];
        S_part[(size_t)T * 128 + tid] = s;
    }
}

// ---------------------------------------------------------------------------
// Kernel 2: hi-bf16 MFMA cosine SCREEN + fused reduce_S.
// R20: EXACT restoration of the R17 structure (best measured: 78.3 us).
// R18 (dbuf) and R19 (256-row blocks) both regressed via occupancy loss —
// this kernel wants many small co-resident blocks.
// Screen: pair-screen (top-2 of col-pair maxes). Zero-C MFMA on ks=0.
// ---------------------------------------------------------------------------
__launch_bounds__(256, 2)
__global__ void gemm_topk_kernel(const char* __restrict__ sess2,
                                 const char* __restrict__ pool2,
                                 u64* __restrict__ partials,
                                 const float* __restrict__ S_part,
                                 float* __restrict__ S) {
    __shared__ char lds[TILEB];

    const int tid = threadIdx.x;
    const int pc  = blockIdx.x;
    const int mt  = blockIdx.y;

    if (mt == 16) {               // ---- reduce_S path: 64 blocks, 2 dims each
        float* part = (float*)lds;
        #pragma unroll
        for (int d2 = 0; d2 < 2; ++d2) {
            int d = pc * 2 + d2;
            float s = 0.f;
            for (int T = tid; T < NT; T += 256)
                s += S_part[(size_t)T * 128 + d];
            part[tid] = s;
            __syncthreads();
            for (int o = 128; o > 0; o >>= 1) {
                if (tid < o) part[tid] += part[tid + o];
                __syncthreads();
            }
            if (tid == 0) S[d] = part[0];
            __syncthreads();
        }
        return;
    }

    const int w   = tid >> 6;
    const int L   = tid & 63;
    const int q   = L >> 4;
    const int l15 = L & 15;
    const int l7  = L & 7;
    const int rowbase = mt * 128 + w * 32;

    short8 afrag[2][4];
    #pragma unroll
    for (int i = 0; i < 2; ++i)
        #pragma unroll
        for (int ks = 0; ks < 4; ++ks)
            afrag[i][ks] = *(const short8*)(sess2 +
                (size_t)(rowbase + i * 16 + l15) * 256 + (ks * 4 + q) * 16);

    int soks[4];
    #pragma unroll
    for (int ks = 0; ks < 4; ++ks) soks[ks] = ((ks * 4 + q) ^ l7) * 16;
    const char* lbase = lds + l15 * 256;

    const f32x4 fz = {0.f, 0.f, 0.f, 0.f};   // persistent zero C-operand

    float key0[2][4], key1[2][4];
    #pragma unroll
    for (int i = 0; i < 2; ++i)
        #pragma unroll
        for (int r = 0; r < 4; ++r)
            key0[i][r] = key1[i][r] = -1e30f;

    int tloc = 0;
    for (int T = pc; T < NT; T += NPC, ++tloc) {
        __syncthreads();
        const char* tb = pool2 + (size_t)T * TILEB;
        #pragma unroll
        for (int rr = 0; rr < 8; ++rr) {
            int idx = rr * 256 + tid;
            async16(tb + idx * 16, lds + idx * 16);
        }
        __syncthreads();

        #pragma unroll
        for (int qt = 0; qt < 4; ++qt) {
            f32x4 acc[2][2];
            {   // ks = 0: C = zero register (no acc init movs)
                const char* cb = lbase + qt * 8192 + soks[0];
                short8 b0 = *(const short8*)(cb);
                short8 b1 = *(const short8*)(cb + 16 * 256);
                #pragma unroll
                for (int i = 0; i < 2; ++i) {
                    acc[i][0] = __builtin_amdgcn_mfma_f32_16x16x32_bf16(
                        afrag[i][0], b0, fz, 0, 0, 0);
                    acc[i][1] = __builtin_amdgcn_mfma_f32_16x16x32_bf16(
                        afrag[i][0], b1, fz, 0, 0, 0);
                }
            }
            #pragma unroll
            for (int ks = 1; ks < 4; ++ks) {
                const char* cb = lbase + qt * 8192 + soks[ks];
                short8 b0 = *(const short8*)(cb);
                short8 b1 = *(const short8*)(cb + 16 * 256);
                #pragma unroll
                for (int i = 0; i < 2; ++i) {
                    acc[i][0] = __builtin_amdgcn_mfma_f32_16x16x32_bf16(
                        afrag[i][ks], b0, acc[i][0], 0, 0, 0);
                    acc[i][1] = __builtin_amdgcn_mfma_f32_16x16x32_bf16(
                        afrag[i][ks], b1, acc[i][1], 0, 0, 0);
                }
            }
            // pair screen: merge j=0/j=1 (cols 16 apart), top-2 insert
            const unsigned ppos = (unsigned)(tloc * 4 + qt);   // 6 bits
            #pragma unroll
            for (int i = 0; i < 2; ++i)
                #pragma unroll
                for (int r = 0; r < 4; ++r) {
                    float v  = fmaxf(acc[i][0][r], acc[i][1][r]);
                    float kf = __uint_as_float(
                        (__float_as_uint(v) & 0xFFFFFFC0u) | ppos);
                    float o0 = key0[i][r];
                    key1[i][r] = __builtin_amdgcn_fmed3f(kf, o0, key1[i][r]);
                    key0[i][r] = fmaxf(o0, kf);
                }
        }
    }

    #pragma unroll
    for (int i = 0; i < 2; ++i)
        #pragma unroll
        for (int r = 0; r < 4; ++r) {
            float kk[2] = {key0[i][r], key1[i][r]};
            u64 t0 = 0ull, t1 = 0ull, t2 = 0ull;
            #pragma unroll
            for (int k = 0; k < 2; ++k) {
                unsigned u   = __float_as_uint(kk[k]);
                unsigned pos = u & 63u;                 // tloc*4 + qt
                unsigned vb  = u & 0xFFFFFFC0u;
                unsigned mono = (vb & 0x80000000u) ? ~vb : (vb | 0x80000000u);
                // col of the j=0 member of the pair; partner is col+16
                unsigned col = (unsigned)((pc + (int)(pos >> 2) * NPC) * 128
                                          + (int)(pos & 3u) * 32 + l15);
                u64 key = ((u64)mono << 32) | (u64)(131071u - col);
                kins64(key, t0, t1, t2);
            }
            #pragma unroll
            for (int m = 1; m < 16; m <<= 1) {
                u64 r0 = __shfl_xor(t0, m);
                u64 r1 = __shfl_xor(t1, m);
                u64 r2 = __shfl_xor(t2, m);
                kins64(r0, t0, t1, t2);
                kins64(r1, t0, t1, t2);
                kins64(r2, t0, t1, t2);
            }
            if (l15 == 0) {
                int row = rowbase + i * 16 + q * 4 + r;
                u64* o = partials + ((size_t)row * NPC + pc) * 3;
                o[0] = t0; o[1] = t1; o[2] = t2;
            }
        }
}

// ---------------------------------------------------------------------------
// Kernel 3 (R20 rewrite): WAVE-PER-ROW, barrier-free. 512 blocks x 4 waves.
// Identical math to the block-phase version (fp64, same tie-breaks; result
// is insertion-order independent since all candidate indices are distinct):
//  - 192 keys live in 3 regs/lane; top-8 via 8 wave-max butterflies
//  - rescore both pair members concurrently in 32-lane halves, per-lane
//    ins3d over the half's 8 candidates + one cross-half merge
//  - weights computed redundantly in every lane (no tid==0 serial phase,
//    which previously idled 255 lanes through 5 fp64 exps + 16 ins3d)
//  - zero __syncthreads, zero LDS
// ---------------------------------------------------------------------------
__launch_bounds__(256)
__global__ void finalize_kernel(const float* __restrict__ sess,
                                const float* __restrict__ pool,
                                const u64* __restrict__ partials,
                                const float* __restrict__ S,
                                float* __restrict__ out_neighbor,
                                float* __restrict__ out_costopk,
                                float* __restrict__ out_sesstopk) {
    const int tid = threadIdx.x;
    const int w   = tid >> 6;
    const int L   = tid & 63;
    const int row = blockIdx.x * 4 + w;

    // ---- 192 screened keys, 3 per lane ----
    const u64* pr = partials + (size_t)row * NCAND;
    u64 a0 = pr[L], a1 = pr[L + 64], a2 = pr[L + 128];

    // ---- session norm + dss (fp64 64-lane butterfly) ----
    float2 sa2 = ((const float2*)(sess + (size_t)row * D_DIM))[L];
    double na  = (double)sa2.x * sa2.x + (double)sa2.y * sa2.y;
    double dss = (double)sa2.x * S[2 * L] + (double)sa2.y * S[2 * L + 1];
    #pragma unroll
    for (int o = 32; o > 0; o >>= 1) {
        na  += __shfl_xor(na, o);
        dss += __shfl_xor(dss, o);
    }
    na += (double)D_DIM * 1e-6;

    // ---- exact top-8 keys via 8 wave-max extractions ----
    u64 top8[8];
    #pragma unroll
    for (int k = 0; k < 8; ++k) {
        u64 m = a0 > a1 ? a0 : a1;
        m = m > a2 ? m : a2;
        u64 g = m;
        #pragma unroll
        for (int o = 1; o < 64; o <<= 1) {
            u64 r = __shfl_xor(g, o);
            g = (r > g) ? r : g;
        }
        if (m == g && g != 0ull) {          // keys are unique: at most one owner
            if (a0 == g)      a0 = 0ull;
            else if (a1 == g) a1 = 0ull;
            else              a2 = 0ull;
        }
        top8[k] = g;
    }

    // ---- exact fp64 rescore: pair k -> cols base (h=0), base+16 (h=1) ----
    const int h   = L >> 5;
    const int l31 = L & 31;
    float4 sa4 = ((const float4*)(sess + (size_t)row * D_DIM))[l31];
    double v0 = -1e300, v1 = -1e300, v2 = -1e300;
    int    i0 = 0x7fffffff, i1 = 0x7fffffff, i2 = 0x7fffffff;
    #pragma unroll
    for (int k = 0; k < 8; ++k) {
        int base = 131071 - (int)(top8[k] & 0x1FFFFull);
        int idx  = base + h * 16;
        bool ok  = (unsigned)idx < (unsigned)P_ROWS;
        float4 pb = ok ? ((const float4*)(pool + (size_t)idx * D_DIM))[l31]
                       : make_float4(0.f, 0.f, 0.f, 0.f);
        double dot = (double)sa4.x * pb.x + (double)sa4.y * pb.y
                   + (double)sa4.z * pb.z + (double)sa4.w * pb.w;
        double nb  = (double)pb.x * pb.x + (double)pb.y * pb.y
                   + (double)pb.z * pb.z + (double)pb.w * pb.w;
        #pragma unroll
        for (int o = 16; o > 0; o >>= 1) {   // 32-lane half reduce
            dot += __shfl_xor(dot, o);
            nb  += __shfl_xor(nb, o);
        }
        double vk = ok ? dot / sqrt(na * (nb + (double)D_DIM * 1e-6)) : -1e300;
        ins3d(vk, idx, v0, i0, v1, i1, v2, i2);
    }
    {   // cross-half merge of the two per-half top-3s
        double mv0 = __shfl_xor(v0, 32), mv1 = __shfl_xor(v1, 32), mv2 = __shfl_xor(v2, 32);
        int    mi0 = __shfl_xor(i0, 32), mi1 = __shfl_xor(i1, 32), mi2 = __shfl_xor(i2, 32);
        ins3d(mv0, mi0, v0, i0, v1, i1, v2, i2);
        ins3d(mv1, mi1, v0, i0, v1, i1, v2, i2);
        ins3d(mv2, mi2, v0, i0, v1, i1, v2, i2);
    }

    // ---- softmax weights (redundant per lane; same fp64 math as before) ----
    double z  = (double)P_ROWS + dss / sqrt(na) + 390.625;
    double c0 = exp(v0) / z, c1 = exp(v1) / z, c2 = exp(v2) / z;
    double e1 = exp(c1 - c0), e2 = exp(c2 - c0);
    double inv = 1.0 / (1.0 + e1 + e2);
    float w0 = (float)inv;
    float w1 = (float)(e1 * inv);
    float w2 = (float)(e2 * inv);

    // ---- outputs: 64 lanes x float2 = 128 dims ----
    float2 g0 = ((const float2*)(pool + (size_t)i0 * D_DIM))[L];
    float2 g1 = ((const float2*)(pool + (size_t)i1 * D_DIM))[L];
    float2 g2 = ((const float2*)(pool + (size_t)i2 * D_DIM))[L];
    ((float2*)(out_sesstopk + ((size_t)row * 3 + 0) * D_DIM))[L] = g0;
    ((float2*)(out_sesstopk + ((size_t)row * 3 + 1) * D_DIM))[L] = g1;
    ((float2*)(out_sesstopk + ((size_t)row * 3 + 2) * D_DIM))[L] = g2;
    float2 nbv;
    nbv.x = w0 * g0.x + w1 * g1.x + w2 * g2.x;
    nbv.y = w0 * g0.y + w1 * g1.y + w2 * g2.y;
    ((float2*)(out_neighbor + (size_t)row * D_DIM))[L] = nbv;
    if (L < 3) out_costopk[row * 3 + L] = (L == 0) ? w0 : ((L == 1) ? w1 : w2);
}

// ---------------------------------------------------------------------------
extern "C" void kernel_launch(void* const* d_in, const int* in_sizes, int n_in,
                              void* d_out, int out_size, void* d_ws, size_t ws_size,
                              hipStream_t stream) {
    const float* sess = (const float*)d_in[0];   // [2048,128]
    const float* pool = (const float*)d_in[1];   // [100000,128]
    float* out = (float*)d_out;
    float* out_neighbor = out;
    float* out_costopk  = out + (size_t)B_ROWS * D_DIM;
    float* out_sesstopk = out_costopk + (size_t)B_ROWS * 3;

    // ws: S(512B) | S_part(400KB) | partials(3.1MB) | sess2(512KB) | pool2(25.6MB)
    float* Svec     = (float*)d_ws;
    float* S_part   = (float*)((char*)d_ws + 512);
    u64*   partials = (u64*)((char*)d_ws + 512 + (size_t)NT * 128 * 4);
    char*  sess2    = (char*)partials + (size_t)B_ROWS * NCAND * 8;
    char*  pool2    = sess2 + (size_t)B_ROWS * 256;

    pack_kernel<<<NT + 512, 256, 0, stream>>>(sess, pool, sess2, pool2, S_part);

    dim3 g3(NPC, 17);
    gemm_topk_kernel<<<g3, 256, 0, stream>>>(sess2, pool2, partials, S_part, Svec);

    finalize_kernel<<<B_ROWS / 4, 256, 0, stream>>>(
        sess, pool, partials, Svec, out_neighbor, out_costopk, out_sesstopk);
}

// Round 6
// 186.398 us; speedup vs baseline: 1.0192x; 1.0192x over previous
//
#include <hip/hip_runtime.h>
#include <math.h>

#define B_ROWS 2048
#define P_ROWS 100000
#define D_DIM  128
#define NPC    64                 // pool chunks (grid.x of gemm)
#define NT     782                // 128-row pool tiles
#define TILEB  32768              // 128 pool-rows x 128 bf16 (256 B/row)
#define HALFB  16384              // half tile (64 pool rows)
#define NCAND  (NPC * 3)          // 192 screened candidates (pairs) per row

typedef short short8 __attribute__((ext_vector_type(8)));
typedef float f32x4  __attribute__((ext_vector_type(4)));
typedef unsigned long long u64;

// bf16 RNE
__device__ __forceinline__ unsigned short f2bf(float f) {
    unsigned u = __float_as_uint(f);
    u += 0x7fffu + ((u >> 16) & 1u);
    return (unsigned short)(u >> 16);
}

__device__ __forceinline__ void async16(const char* g, char* l) {
    __builtin_amdgcn_global_load_lds(
        (const __attribute__((address_space(1))) unsigned int*)g,
        (__attribute__((address_space(3))) unsigned int*)l,
        16, 0, 0);
}

// u64 branchless top-3 insert
__device__ __forceinline__ void kins64(u64 k, u64& t0, u64& t1, u64& t2) {
    u64 m0 = (t0 < k) ? t0 : k;  t0 = (t0 < k) ? k : t0;
    u64 m1 = (t1 < m0) ? t1 : m0; t1 = (t1 < m0) ? m0 : t1;
    t2 = (t2 < m1) ? m1 : t2;
}

// fp64 top-3 insert with index tie-break (lower index wins)
__device__ __forceinline__ void ins3d(double v, int c,
                                      double& v0, int& i0,
                                      double& v1, int& i1,
                                      double& v2, int& i2) {
    bool b0 = (v > v0) || (v == v0 && c < i0);
    bool b1 = (v > v1) || (v == v1 && c < i1);
    bool b2 = (v > v2) || (v == v2 && c < i2);
    if (b0)      { v2 = v1; i2 = i1; v1 = v0; i1 = i0; v0 = v; i0 = c; }
    else if (b1) { v2 = v1; i2 = i1; v1 = v;  i1 = c; }
    else if (b2) { v2 = v;  i2 = c; }
}

// ---------------------------------------------------------------------------
// Kernel 1 (R15 merged): blocks [0,NT) pack pool; blocks [NT,NT+512) pack
// sess. Pool path is SINGLE-PASS: row norm via 4-step shfl_xor inside the
// 16-lane row group. One barrier at the end for the per-block S partial.
// ---------------------------------------------------------------------------
__global__ void pack_kernel(const float* __restrict__ sess,
                            const float* __restrict__ pool,
                            char* __restrict__ sess2,
                            char* __restrict__ pool2,
                            float* __restrict__ S_part) {
    const int tid = threadIdx.x;
    const int bx  = blockIdx.x;

    if (bx >= NT) {               // ---- sess path: one wave per row ----
        int row  = (bx - NT) * 4 + (tid >> 6);
        int lane = tid & 63;
        float2 v = ((const float2*)(sess + (size_t)row * D_DIM))[lane];
        float s = v.x * v.x + v.y * v.y;
        #pragma unroll
        for (int o = 32; o > 0; o >>= 1) s += __shfl_xor(s, o);
        float inv = 1.0f / sqrtf(s + (float)D_DIM * 1e-6f);
        ushort2 hv;
        hv.x = f2bf(v.x * inv);
        hv.y = f2bf(v.y * inv);
        *(ushort2*)(sess2 + (size_t)row * 256 + lane * 4) = hv;
        return;
    }

    // ---- pool path ----
    __shared__ float red2[16][128];
    const int T  = bx;
    const int c0 = tid >> 4;      // row-in-iteration (16 rows/iter)
    const int g  = tid & 15;      // 8-elem group within the row

    float sacc[8] = {0.f,0.f,0.f,0.f,0.f,0.f,0.f,0.f};
    #pragma unroll
    for (int it = 0; it < 8; ++it) {
        int c = it * 16 + c0;
        int n = T * 128 + c;
        float4 a = make_float4(0.f, 0.f, 0.f, 0.f), b = a;
        if (n < P_ROWS) {
            const float4* src = (const float4*)(pool + (size_t)n * D_DIM + g * 8);
            a = src[0]; b = src[1];
        }
        float s = a.x*a.x + a.y*a.y + a.z*a.z + a.w*a.w
                + b.x*b.x + b.y*b.y + b.z*b.z + b.w*b.w;
        // row-sum across the 16 lanes owning row c (aligned 16-lane group)
        s += __shfl_xor(s, 1);
        s += __shfl_xor(s, 2);
        s += __shfl_xor(s, 4);
        s += __shfl_xor(s, 8);
        float inv = 1.0f / sqrtf(s + (float)D_DIM * 1e-6f);
        const float f[8] = {a.x, a.y, a.z, a.w, b.x, b.y, b.z, b.w};
        short8 hv;
        #pragma unroll
        for (int j = 0; j < 8; ++j) {
            float w = f[j] * inv;
            hv[j] = (short)f2bf(w);
            sacc[j] += w;
        }
        *(short8*)(pool2 + (size_t)T * TILEB + c * 256 + ((g ^ (c & 7)) * 16)) = hv;
    }
    #pragma unroll
    for (int j = 0; j < 8; ++j) red2[c0][g * 8 + j] = sacc[j];
    __syncthreads();
    if (tid < 128) {
        float s = 0.f;
        #pragma unroll
        for (int k = 0; k < 16; ++k) s += red2[k][tid];
        S_part[(size_t)T * 128 + tid] = s;
    }
}

// ---------------------------------------------------------------------------
// Kernel 2: hi-bf16 MFMA cosine SCREEN + fused reduce_S.
// R21: HALF-TILE 2-PHASE PIPELINE, SAME 32KB LDS. R18's full dbuf removed
// the per-tile vmcnt(0) drain but paid 2x LDS + 40 VGPR -> occupancy 19%,
// regression. Here the tile is split into two 16KB halves rotating through
// two half-buffers: per half {barrier; issue next half's 4 gl_lds into the
// other half-buffer; s_waitcnt vmcnt(4) counted; barrier; compute 2 qt}.
// LDS stays 32KB, VGPR ~48, grid unchanged -> occupancy preserved while
// loads stay in flight across barriers (T4: counted, never 0 mid-loop).
// Row mapping is unchanged: tile row = 32*qt + l15, swizzle row&7 = l15&7.
// Screen: pair-screen (top-2 of col-pair maxes). Zero-C MFMA on ks=0.
// ---------------------------------------------------------------------------
__launch_bounds__(256, 2)
__global__ void gemm_topk_kernel(const char* __restrict__ sess2,
                                 const char* __restrict__ pool2,
                                 u64* __restrict__ partials,
                                 const float* __restrict__ S_part,
                                 float* __restrict__ S) {
    __shared__ char lds[TILEB];

    const int tid = threadIdx.x;
    const int pc  = blockIdx.x;
    const int mt  = blockIdx.y;

    if (mt == 16) {               // ---- reduce_S path: 64 blocks, 2 dims each
        float* part = (float*)lds;
        #pragma unroll
        for (int d2 = 0; d2 < 2; ++d2) {
            int d = pc * 2 + d2;
            float s = 0.f;
            for (int T = tid; T < NT; T += 256)
                s += S_part[(size_t)T * 128 + d];
            part[tid] = s;
            __syncthreads();
            for (int o = 128; o > 0; o >>= 1) {
                if (tid < o) part[tid] += part[tid + o];
                __syncthreads();
            }
            if (tid == 0) S[d] = part[0];
            __syncthreads();
        }
        return;
    }

    const int w   = tid >> 6;
    const int L   = tid & 63;
    const int q   = L >> 4;
    const int l15 = L & 15;
    const int l7  = L & 7;
    const int rowbase = mt * 128 + w * 32;

    short8 afrag[2][4];
    #pragma unroll
    for (int i = 0; i < 2; ++i)
        #pragma unroll
        for (int ks = 0; ks < 4; ++ks)
            afrag[i][ks] = *(const short8*)(sess2 +
                (size_t)(rowbase + i * 16 + l15) * 256 + (ks * 4 + q) * 16);

    int soks[4];
    #pragma unroll
    for (int ks = 0; ks < 4; ++ks) soks[ks] = ((ks * 4 + q) ^ l7) * 16;

    const f32x4 fz = {0.f, 0.f, 0.f, 0.f};   // persistent zero C-operand

    float key0[2][4], key1[2][4];
    #pragma unroll
    for (int i = 0; i < 2; ++i)
        #pragma unroll
        for (int r = 0; r < 4; ++r)
            key0[i][r] = key1[i][r] = -1e30f;

    const int nt_this = (NT - 1 - pc) / NPC + 1;   // 12 or 13 tiles
    const int NH = nt_this * 2;                    // half-tile stream

    // prologue: stage half 0 (tile pc, rows 0-63) into half-buffer 0
    {
        const char* tb = pool2 + (size_t)pc * TILEB;
        #pragma unroll
        for (int rr = 0; rr < 4; ++rr) {
            int idx = rr * 256 + tid;
            async16(tb + idx * 16, lds + idx * 16);
        }
    }

    for (int H = 0; H < NH; ++H) {
        const int buf = H & 1;

        // barrier #1: everyone done computing the other half-buffer
        __builtin_amdgcn_s_barrier();
        asm volatile("" ::: "memory");

        const int Hn = H + 1;
        if (Hn < NH) {
            const int Tn = pc + (Hn >> 1) * NPC;
            const char* tb = pool2 + (size_t)Tn * TILEB + (size_t)(Hn & 1) * HALFB;
            char* dst = lds + (Hn & 1) * HALFB;
            #pragma unroll
            for (int rr = 0; rr < 4; ++rr) {
                int idx = rr * 256 + tid;
                async16(tb + idx * 16, dst + idx * 16);
            }
            // counted: my current half's 4 oldest loads retired; next
            // half's 4 stay in flight across the barrier (T4)
            asm volatile("s_waitcnt vmcnt(4)" ::: "memory");
        } else {
            asm volatile("s_waitcnt vmcnt(0)" ::: "memory");
        }
        // barrier #2: all waves' DMA for half H visible
        __builtin_amdgcn_s_barrier();
        asm volatile("" ::: "memory");

        const char* lb = lds + buf * HALFB + l15 * 256;
        const int tloc = H >> 1;

        #pragma unroll
        for (int sub = 0; sub < 2; ++sub) {
            const int qt = (buf << 1) + sub;       // global qt 0..3
            f32x4 acc[2][2];
            {   // ks = 0: C = zero register (no acc init movs)
                const char* cb = lb + sub * 8192 + soks[0];
                short8 b0 = *(const short8*)(cb);
                short8 b1 = *(const short8*)(cb + 16 * 256);
                #pragma unroll
                for (int i = 0; i < 2; ++i) {
                    acc[i][0] = __builtin_amdgcn_mfma_f32_16x16x32_bf16(
                        afrag[i][0], b0, fz, 0, 0, 0);
                    acc[i][1] = __builtin_amdgcn_mfma_f32_16x16x32_bf16(
                        afrag[i][0], b1, fz, 0, 0, 0);
                }
            }
            #pragma unroll
            for (int ks = 1; ks < 4; ++ks) {
                const char* cb = lb + sub * 8192 + soks[ks];
                short8 b0 = *(const short8*)(cb);
                short8 b1 = *(const short8*)(cb + 16 * 256);
                #pragma unroll
                for (int i = 0; i < 2; ++i) {
                    acc[i][0] = __builtin_amdgcn_mfma_f32_16x16x32_bf16(
                        afrag[i][ks], b0, acc[i][0], 0, 0, 0);
                    acc[i][1] = __builtin_amdgcn_mfma_f32_16x16x32_bf16(
                        afrag[i][ks], b1, acc[i][1], 0, 0, 0);
                }
            }
            // pair screen: merge j=0/j=1 (cols 16 apart), top-2 insert
            const unsigned ppos = (unsigned)(tloc * 4 + qt);   // 6 bits
            #pragma unroll
            for (int i = 0; i < 2; ++i)
                #pragma unroll
                for (int r = 0; r < 4; ++r) {
                    float v  = fmaxf(acc[i][0][r], acc[i][1][r]);
                    float kf = __uint_as_float(
                        (__float_as_uint(v) & 0xFFFFFFC0u) | ppos);
                    float o0 = key0[i][r];
                    key1[i][r] = __builtin_amdgcn_fmed3f(kf, o0, key1[i][r]);
                    key0[i][r] = fmaxf(o0, kf);
                }
        }
    }

    #pragma unroll
    for (int i = 0; i < 2; ++i)
        #pragma unroll
        for (int r = 0; r < 4; ++r) {
            float kk[2] = {key0[i][r], key1[i][r]};
            u64 t0 = 0ull, t1 = 0ull, t2 = 0ull;
            #pragma unroll
            for (int k = 0; k < 2; ++k) {
                unsigned u   = __float_as_uint(kk[k]);
                unsigned pos = u & 63u;                 // tloc*4 + qt
                unsigned vb  = u & 0xFFFFFFC0u;
                unsigned mono = (vb & 0x80000000u) ? ~vb : (vb | 0x80000000u);
                // col of the j=0 member of the pair; partner is col+16
                unsigned col = (unsigned)((pc + (int)(pos >> 2) * NPC) * 128
                                          + (int)(pos & 3u) * 32 + l15);
                u64 key = ((u64)mono << 32) | (u64)(131071u - col);
                kins64(key, t0, t1, t2);
            }
            #pragma unroll
            for (int m = 1; m < 16; m <<= 1) {
                u64 r0 = __shfl_xor(t0, m);
                u64 r1 = __shfl_xor(t1, m);
                u64 r2 = __shfl_xor(t2, m);
                kins64(r0, t0, t1, t2);
                kins64(r1, t0, t1, t2);
                kins64(r2, t0, t1, t2);
            }
            if (l15 == 0) {
                int row = rowbase + i * 16 + q * 4 + r;
                u64* o = partials + ((size_t)row * NPC + pc) * 3;
                o[0] = t0; o[1] = t1; o[2] = t2;
            }
        }
}

// ---------------------------------------------------------------------------
// Kernel 3: one row per block (R17 version — best measured total). Top-8
// keys are PAIRS -> rescore both columns of each pair (16 candidates) using
// half-wave (32-lane) reductions.
// ---------------------------------------------------------------------------
__launch_bounds__(256)
__global__ void finalize_kernel(const float* __restrict__ sess,
                                const float* __restrict__ pool,
                                const u64* __restrict__ partials,
                                const float* __restrict__ S,
                                float* __restrict__ out_neighbor,
                                float* __restrict__ out_costopk,
                                float* __restrict__ out_sesstopk) {
    __shared__ u64    keys[NCAND];
    __shared__ u64    top8[8];
    __shared__ double vv[16];
    __shared__ int    ii[16];
    __shared__ double s_na, s_dss;
    __shared__ float  s_w[3];
    __shared__ int    s_i[3];

    const int row = blockIdx.x;
    const int tid = threadIdx.x;
    const int w   = tid >> 6;
    const int L   = tid & 63;

    if (tid < NCAND) keys[tid] = partials[(size_t)row * NCAND + tid];
    if (w == 3) {
        float2 sa = ((const float2*)(sess + (size_t)row * D_DIM))[L];
        double na  = (double)sa.x * sa.x + (double)sa.y * sa.y;
        double dss = (double)sa.x * S[2 * L] + (double)sa.y * S[2 * L + 1];
        #pragma unroll
        for (int o = 32; o > 0; o >>= 1) {
            na  += __shfl_xor(na, o);
            dss += __shfl_xor(dss, o);
        }
        if (L == 0) { s_na = na + (double)D_DIM * 1e-6; s_dss = dss; }
    }
    __syncthreads();

    if (w == 0) {
        for (int k = 0; k < 8; ++k) {
            u64 a0 = keys[L], a1 = keys[L + 64], a2 = keys[L + 128];
            u64 m = a0 > a1 ? a0 : a1;
            m = m > a2 ? m : a2;
            u64 g = m;
            #pragma unroll
            for (int o = 1; o < 64; o <<= 1) {
                u64 r = __shfl_xor(g, o);
                g = (r > g) ? r : g;
            }
            if (m == g && g != 0ull) {
                if (a0 == g)      keys[L] = 0ull;
                else if (a1 == g) keys[L + 64] = 0ull;
                else              keys[L + 128] = 0ull;
            }
            if (L == 0) top8[k] = g;
        }
    }
    __syncthreads();

    {   // rescore: pair c -> columns base (h=0) and base+16 (h=1)
        const int h   = L >> 5;
        const int l31 = L & 31;
        float4 sa = ((const float4*)(sess + (size_t)row * D_DIM))[l31];
        #pragma unroll
        for (int cc = 0; cc < 2; ++cc) {
            int c = 2 * w + cc;
            int base = 131071 - (int)(top8[c] & 0x1FFFFull);
            int idx  = base + h * 16;
            bool ok  = (unsigned)idx < (unsigned)P_ROWS;
            float4 pb = ok ? ((const float4*)(pool + (size_t)idx * D_DIM))[l31]
                           : make_float4(0.f, 0.f, 0.f, 0.f);
            double dot = (double)sa.x * pb.x + (double)sa.y * pb.y
                       + (double)sa.z * pb.z + (double)sa.w * pb.w;
            double nb  = (double)pb.x * pb.x + (double)pb.y * pb.y
                       + (double)pb.z * pb.z + (double)pb.w * pb.w;
            #pragma unroll
            for (int o = 16; o > 0; o >>= 1) {
                dot += __shfl_xor(dot, o);
                nb  += __shfl_xor(nb, o);
            }
            if (l31 == 0) {
                vv[c * 2 + h] = ok ? dot / sqrt(s_na * (nb + (double)D_DIM * 1e-6))
                                   : -1e300;
                ii[c * 2 + h] = idx;
            }
        }
    }
    __syncthreads();

    if (tid == 0) {
        double v0 = -1e300, v1 = -1e300, v2 = -1e300;
        int    i0 = 0x7fffffff, i1 = 0x7fffffff, i2 = 0x7fffffff;
        for (int j = 0; j < 16; ++j) ins3d(vv[j], ii[j], v0, i0, v1, i1, v2, i2);
        double z  = (double)P_ROWS + s_dss / sqrt(s_na) + 390.625;
        double c0 = exp(v0) / z, c1 = exp(v1) / z, c2 = exp(v2) / z;
        double e1 = exp(c1 - c0), e2 = exp(c2 - c0);
        double inv = 1.0 / (1.0 + e1 + e2);
        s_w[0] = (float)inv;
        s_w[1] = (float)(e1 * inv);
        s_w[2] = (float)(e2 * inv);
        s_i[0] = i0; s_i[1] = i1; s_i[2] = i2;
    }
    __syncthreads();

    if (tid < D_DIM) {
        float g0 = pool[(size_t)s_i[0] * D_DIM + tid];
        float g1 = pool[(size_t)s_i[1] * D_DIM + tid];
        float g2 = pool[(size_t)s_i[2] * D_DIM + tid];
        out_sesstopk[((size_t)row * 3 + 0) * D_DIM + tid] = g0;
        out_sesstopk[((size_t)row * 3 + 1) * D_DIM + tid] = g1;
        out_sesstopk[((size_t)row * 3 + 2) * D_DIM + tid] = g2;
        out_neighbor[(size_t)row * D_DIM + tid] =
            s_w[0] * g0 + s_w[1] * g1 + s_w[2] * g2;
        if (tid < 3) out_costopk[row * 3 + tid] = s_w[tid];
    }
}

// ---------------------------------------------------------------------------
extern "C" void kernel_launch(void* const* d_in, const int* in_sizes, int n_in,
                              void* d_out, int out_size, void* d_ws, size_t ws_size,
                              hipStream_t stream) {
    const float* sess = (const float*)d_in[0];   // [2048,128]
    const float* pool = (const float*)d_in[1];   // [100000,128]
    float* out = (float*)d_out;
    float* out_neighbor = out;
    float* out_costopk  = out + (size_t)B_ROWS * D_DIM;
    float* out_sesstopk = out_costopk + (size_t)B_ROWS * 3;

    // ws: S(512B) | S_part(400KB) | partials(3.1MB) | sess2(512KB) | pool2(25.6MB)
    float* Svec     = (float*)d_ws;
    float* S_part   = (float*)((char*)d_ws + 512);
    u64*   partials = (u64*)((char*)d_ws + 512 + (size_t)NT * 128 * 4);
    char*  sess2    = (char*)partials + (size_t)B_ROWS * NCAND * 8;
    char*  pool2    = sess2 + (size_t)B_ROWS * 256;

    pack_kernel<<<NT + 512, 256, 0, stream>>>(sess, pool, sess2, pool2, S_part);

    dim3 g3(NPC, 17);
    gemm_topk_kernel<<<g3, 256, 0, stream>>>(sess2, pool2, partials, S_part, Svec);

    finalize_kernel<<<B_ROWS, 256, 0, stream>>>(
        sess, pool, partials, Svec, out_neighbor, out_costopk, out_sesstopk);
}

// Round 8
// 184.968 us; speedup vs baseline: 1.0271x; 1.0077x over previous
//
#include <hip/hip_runtime.h>
#include <math.h>

#define B_ROWS 2048
#define P_ROWS 100000
#define D_DIM  128
#define NPC    64                 // pool chunks (grid.x of gemm)
#define NT     782                // 128-row pool tiles
#define TILEB  32768              // 128 pool-rows x 128 bf16 (256 B/row)
#define NCAND  (NPC * 3)          // 192 screened candidates (pairs) per row

typedef short short8 __attribute__((ext_vector_type(8)));
typedef float f32x4  __attribute__((ext_vector_type(4)));
typedef unsigned long long u64;

// bf16 RNE
__device__ __forceinline__ unsigned short f2bf(float f) {
    unsigned u = __float_as_uint(f);
    u += 0x7fffu + ((u >> 16) & 1u);
    return (unsigned short)(u >> 16);
}

__device__ __forceinline__ void async16(const char* g, char* l) {
    __builtin_amdgcn_global_load_lds(
        (const __attribute__((address_space(1))) unsigned int*)g,
        (__attribute__((address_space(3))) unsigned int*)l,
        16, 0, 0);
}

// u64 branchless top-3 insert
__device__ __forceinline__ void kins64(u64 k, u64& t0, u64& t1, u64& t2) {
    u64 m0 = (t0 < k) ? t0 : k;  t0 = (t0 < k) ? k : t0;
    u64 m1 = (t1 < m0) ? t1 : m0; t1 = (t1 < m0) ? m0 : t1;
    t2 = (t2 < m1) ? m1 : t2;
}

// fp64 top-3 insert with index tie-break (lower index wins)
__device__ __forceinline__ void ins3d(double v, int c,
                                      double& v0, int& i0,
                                      double& v1, int& i1,
                                      double& v2, int& i2) {
    bool b0 = (v > v0) || (v == v0 && c < i0);
    bool b1 = (v > v1) || (v == v1 && c < i1);
    bool b2 = (v > v2) || (v == v2 && c < i2);
    if (b0)      { v2 = v1; i2 = i1; v1 = v0; i1 = i0; v0 = v; i0 = c; }
    else if (b1) { v2 = v1; i2 = i1; v1 = v;  i1 = c; }
    else if (b2) { v2 = v;  i2 = c; }
}

// ---------------------------------------------------------------------------
// Kernel 1 (R15 merged): blocks [0,NT) pack pool; blocks [NT,NT+512) pack
// sess. Pool path is SINGLE-PASS: row norm via 4-step shfl_xor inside the
// 16-lane row group. One barrier at the end for the per-block S partial.
// ---------------------------------------------------------------------------
__global__ void pack_kernel(const float* __restrict__ sess,
                            const float* __restrict__ pool,
                            char* __restrict__ sess2,
                            char* __restrict__ pool2,
                            float* __restrict__ S_part) {
    const int tid = threadIdx.x;
    const int bx  = blockIdx.x;

    if (bx >= NT) {               // ---- sess path: one wave per row ----
        int row  = (bx - NT) * 4 + (tid >> 6);
        int lane = tid & 63;
        float2 v = ((const float2*)(sess + (size_t)row * D_DIM))[lane];
        float s = v.x * v.x + v.y * v.y;
        #pragma unroll
        for (int o = 32; o > 0; o >>= 1) s += __shfl_xor(s, o);
        float inv = 1.0f / sqrtf(s + (float)D_DIM * 1e-6f);
        ushort2 hv;
        hv.x = f2bf(v.x * inv);
        hv.y = f2bf(v.y * inv);
        *(ushort2*)(sess2 + (size_t)row * 256 + lane * 4) = hv;
        return;
    }

    // ---- pool path ----
    __shared__ float red2[16][128];
    const int T  = bx;
    const int c0 = tid >> 4;      // row-in-iteration (16 rows/iter)
    const int g  = tid & 15;      // 8-elem group within the row

    float sacc[8] = {0.f,0.f,0.f,0.f,0.f,0.f,0.f,0.f};
    #pragma unroll
    for (int it = 0; it < 8; ++it) {
        int c = it * 16 + c0;
        int n = T * 128 + c;
        float4 a = make_float4(0.f, 0.f, 0.f, 0.f), b = a;
        if (n < P_ROWS) {
            const float4* src = (const float4*)(pool + (size_t)n * D_DIM + g * 8);
            a = src[0]; b = src[1];
        }
        float s = a.x*a.x + a.y*a.y + a.z*a.z + a.w*a.w
                + b.x*b.x + b.y*b.y + b.z*b.z + b.w*b.w;
        // row-sum across the 16 lanes owning row c (aligned 16-lane group)
        s += __shfl_xor(s, 1);
        s += __shfl_xor(s, 2);
        s += __shfl_xor(s, 4);
        s += __shfl_xor(s, 8);
        float inv = 1.0f / sqrtf(s + (float)D_DIM * 1e-6f);
        const float f[8] = {a.x, a.y, a.z, a.w, b.x, b.y, b.z, b.w};
        short8 hv;
        #pragma unroll
        for (int j = 0; j < 8; ++j) {
            float w = f[j] * inv;
            hv[j] = (short)f2bf(w);
            sacc[j] += w;
        }
        *(short8*)(pool2 + (size_t)T * TILEB + c * 256 + ((g ^ (c & 7)) * 16)) = hv;
    }
    #pragma unroll
    for (int j = 0; j < 8; ++j) red2[c0][g * 8 + j] = sacc[j];
    __syncthreads();
    if (tid < 128) {
        float s = 0.f;
        #pragma unroll
        for (int k = 0; k < 16; ++k) s += red2[k][tid];
        S_part[(size_t)T * 128 + tid] = s;
    }
}

// ---------------------------------------------------------------------------
// Kernel 2: hi-bf16 MFMA cosine SCREEN + fused reduce_S.
// R22: R17 structure EXACTLY (best measured 78.3 us), ONE change:
// __launch_bounds__(256,2) -> (256,4). The (256,2) bound dates from R8 when
// the kernel was register-fat; at 48 VGPR the (256,4) budget (128 VGPR) is
// 2.6x headroom and 4x32KB LDS fits in 160KB -> 4 blocks/CU, 16 waves/CU.
// The kernel is latency-bound (no pipe saturated: MFMA 27%, VALU 53%,
// LDS-pipe ~60%); doubling resident blocks doubles the schedulable contexts
// that hide the per-tile stage+drain serial section which R18/R19/R21
// failed to hide intra-block.
// Screen: pair-screen (top-2 of col-pair maxes). Zero-C MFMA on ks=0.
// ---------------------------------------------------------------------------
__launch_bounds__(256, 4)
__global__ void gemm_topk_kernel(const char* __restrict__ sess2,
                                 const char* __restrict__ pool2,
                                 u64* __restrict__ partials,
                                 const float* __restrict__ S_part,
                                 float* __restrict__ S) {
    __shared__ char lds[TILEB];

    const int tid = threadIdx.x;
    const int pc  = blockIdx.x;
    const int mt  = blockIdx.y;

    if (mt == 16) {               // ---- reduce_S path: 64 blocks, 2 dims each
        float* part = (float*)lds;
        #pragma unroll
        for (int d2 = 0; d2 < 2; ++d2) {
            int d = pc * 2 + d2;
            float s = 0.f;
            for (int T = tid; T < NT; T += 256)
                s += S_part[(size_t)T * 128 + d];
            part[tid] = s;
            __syncthreads();
            for (int o = 128; o > 0; o >>= 1) {
                if (tid < o) part[tid] += part[tid + o];
                __syncthreads();
            }
            if (tid == 0) S[d] = part[0];
            __syncthreads();
        }
        return;
    }

    const int w   = tid >> 6;
    const int L   = tid & 63;
    const int q   = L >> 4;
    const int l15 = L & 15;
    const int l7  = L & 7;
    const int rowbase = mt * 128 + w * 32;

    short8 afrag[2][4];
    #pragma unroll
    for (int i = 0; i < 2; ++i)
        #pragma unroll
        for (int ks = 0; ks < 4; ++ks)
            afrag[i][ks] = *(const short8*)(sess2 +
                (size_t)(rowbase + i * 16 + l15) * 256 + (ks * 4 + q) * 16);

    int soks[4];
    #pragma unroll
    for (int ks = 0; ks < 4; ++ks) soks[ks] = ((ks * 4 + q) ^ l7) * 16;
    const char* lbase = lds + l15 * 256;

    const f32x4 fz = {0.f, 0.f, 0.f, 0.f};   // persistent zero C-operand

    float key0[2][4], key1[2][4];
    #pragma unroll
    for (int i = 0; i < 2; ++i)
        #pragma unroll
        for (int r = 0; r < 4; ++r)
            key0[i][r] = key1[i][r] = -1e30f;

    int tloc = 0;
    for (int T = pc; T < NT; T += NPC, ++tloc) {
        __syncthreads();
        const char* tb = pool2 + (size_t)T * TILEB;
        #pragma unroll
        for (int rr = 0; rr < 8; ++rr) {
            int idx = rr * 256 + tid;
            async16(tb + idx * 16, lds + idx * 16);
        }
        __syncthreads();

        #pragma unroll
        for (int qt = 0; qt < 4; ++qt) {
            f32x4 acc[2][2];
            {   // ks = 0: C = zero register (no acc init movs)
                const char* cb = lbase + qt * 8192 + soks[0];
                short8 b0 = *(const short8*)(cb);
                short8 b1 = *(const short8*)(cb + 16 * 256);
                #pragma unroll
                for (int i = 0; i < 2; ++i) {
                    acc[i][0] = __builtin_amdgcn_mfma_f32_16x16x32_bf16(
                        afrag[i][0], b0, fz, 0, 0, 0);
                    acc[i][1] = __builtin_amdgcn_mfma_f32_16x16x32_bf16(
                        afrag[i][0], b1, fz, 0, 0, 0);
                }
            }
            #pragma unroll
            for (int ks = 1; ks < 4; ++ks) {
                const char* cb = lbase + qt * 8192 + soks[ks];
                short8 b0 = *(const short8*)(cb);
                short8 b1 = *(const short8*)(cb + 16 * 256);
                #pragma unroll
                for (int i = 0; i < 2; ++i) {
                    acc[i][0] = __builtin_amdgcn_mfma_f32_16x16x32_bf16(
                        afrag[i][ks], b0, acc[i][0], 0, 0, 0);
                    acc[i][1] = __builtin_amdgcn_mfma_f32_16x16x32_bf16(
                        afrag[i][ks], b1, acc[i][1], 0, 0, 0);
                }
            }
            // pair screen: merge j=0/j=1 (cols 16 apart), top-2 insert
            const unsigned ppos = (unsigned)(tloc * 4 + qt);   // 6 bits
            #pragma unroll
            for (int i = 0; i < 2; ++i)
                #pragma unroll
                for (int r = 0; r < 4; ++r) {
                    float v  = fmaxf(acc[i][0][r], acc[i][1][r]);
                    float kf = __uint_as_float(
                        (__float_as_uint(v) & 0xFFFFFFC0u) | ppos);
                    float o0 = key0[i][r];
                    key1[i][r] = __builtin_amdgcn_fmed3f(kf, o0, key1[i][r]);
                    key0[i][r] = fmaxf(o0, kf);
                }
        }
    }

    #pragma unroll
    for (int i = 0; i < 2; ++i)
        #pragma unroll
        for (int r = 0; r < 4; ++r) {
            float kk[2] = {key0[i][r], key1[i][r]};
            u64 t0 = 0ull, t1 = 0ull, t2 = 0ull;
            #pragma unroll
            for (int k = 0; k < 2; ++k) {
                unsigned u   = __float_as_uint(kk[k]);
                unsigned pos = u & 63u;                 // tloc*4 + qt
                unsigned vb  = u & 0xFFFFFFC0u;
                unsigned mono = (vb & 0x80000000u) ? ~vb : (vb | 0x80000000u);
                // col of the j=0 member of the pair; partner is col+16
                unsigned col = (unsigned)((pc + (int)(pos >> 2) * NPC) * 128
                                          + (int)(pos & 3u) * 32 + l15);
                u64 key = ((u64)mono << 32) | (u64)(131071u - col);
                kins64(key, t0, t1, t2);
            }
            #pragma unroll
            for (int m = 1; m < 16; m <<= 1) {
                u64 r0 = __shfl_xor(t0, m);
                u64 r1 = __shfl_xor(t1, m);
                u64 r2 = __shfl_xor(t2, m);
                kins64(r0, t0, t1, t2);
                kins64(r1, t0, t1, t2);
                kins64(r2, t0, t1, t2);
            }
            if (l15 == 0) {
                int row = rowbase + i * 16 + q * 4 + r;
                u64* o = partials + ((size_t)row * NPC + pc) * 3;
                o[0] = t0; o[1] = t1; o[2] = t2;
            }
        }
}

// ---------------------------------------------------------------------------
// Kernel 3: one row per block (R17 version — best measured total). Top-8
// keys are PAIRS -> rescore both columns of each pair (16 candidates) using
// half-wave (32-lane) reductions.
// ---------------------------------------------------------------------------
__launch_bounds__(256)
__global__ void finalize_kernel(const float* __restrict__ sess,
                                const float* __restrict__ pool,
                                const u64* __restrict__ partials,
                                const float* __restrict__ S,
                                float* __restrict__ out_neighbor,
                                float* __restrict__ out_costopk,
                                float* __restrict__ out_sesstopk) {
    __shared__ u64    keys[NCAND];
    __shared__ u64    top8[8];
    __shared__ double vv[16];
    __shared__ int    ii[16];
    __shared__ double s_na, s_dss;
    __shared__ float  s_w[3];
    __shared__ int    s_i[3];

    const int row = blockIdx.x;
    const int tid = threadIdx.x;
    const int w   = tid >> 6;
    const int L   = tid & 63;

    if (tid < NCAND) keys[tid] = partials[(size_t)row * NCAND + tid];
    if (w == 3) {
        float2 sa = ((const float2*)(sess + (size_t)row * D_DIM))[L];
        double na  = (double)sa.x * sa.x + (double)sa.y * sa.y;
        double dss = (double)sa.x * S[2 * L] + (double)sa.y * S[2 * L + 1];
        #pragma unroll
        for (int o = 32; o > 0; o >>= 1) {
            na  += __shfl_xor(na, o);
            dss += __shfl_xor(dss, o);
        }
        if (L == 0) { s_na = na + (double)D_DIM * 1e-6; s_dss = dss; }
    }
    __syncthreads();

    if (w == 0) {
        for (int k = 0; k < 8; ++k) {
            u64 a0 = keys[L], a1 = keys[L + 64], a2 = keys[L + 128];
            u64 m = a0 > a1 ? a0 : a1;
            m = m > a2 ? m : a2;
            u64 g = m;
            #pragma unroll
            for (int o = 1; o < 64; o <<= 1) {
                u64 r = __shfl_xor(g, o);
                g = (r > g) ? r : g;
            }
            if (m == g && g != 0ull) {
                if (a0 == g)      keys[L] = 0ull;
                else if (a1 == g) keys[L + 64] = 0ull;
                else              keys[L + 128] = 0ull;
            }
            if (L == 0) top8[k] = g;
        }
    }
    __syncthreads();

    {   // rescore: pair c -> columns base (h=0) and base+16 (h=1)
        const int h   = L >> 5;
        const int l31 = L & 31;
        float4 sa = ((const float4*)(sess + (size_t)row * D_DIM))[l31];
        #pragma unroll
        for (int cc = 0; cc < 2; ++cc) {
            int c = 2 * w + cc;
            int base = 131071 - (int)(top8[c] & 0x1FFFFull);
            int idx  = base + h * 16;
            bool ok  = (unsigned)idx < (unsigned)P_ROWS;
            float4 pb = ok ? ((const float4*)(pool + (size_t)idx * D_DIM))[l31]
                           : make_float4(0.f, 0.f, 0.f, 0.f);
            double dot = (double)sa.x * pb.x + (double)sa.y * pb.y
                       + (double)sa.z * pb.z + (double)sa.w * pb.w;
            double nb  = (double)pb.x * pb.x + (double)pb.y * pb.y
                       + (double)pb.z * pb.z + (double)pb.w * pb.w;
            #pragma unroll
            for (int o = 16; o > 0; o >>= 1) {
                dot += __shfl_xor(dot, o);
                nb  += __shfl_xor(nb, o);
            }
            if (l31 == 0) {
                vv[c * 2 + h] = ok ? dot / sqrt(s_na * (nb + (double)D_DIM * 1e-6))
                                   : -1e300;
                ii[c * 2 + h] = idx;
            }
        }
    }
    __syncthreads();

    if (tid == 0) {
        double v0 = -1e300, v1 = -1e300, v2 = -1e300;
        int    i0 = 0x7fffffff, i1 = 0x7fffffff, i2 = 0x7fffffff;
        for (int j = 0; j < 16; ++j) ins3d(vv[j], ii[j], v0, i0, v1, i1, v2, i2);
        double z  = (double)P_ROWS + s_dss / sqrt(s_na) + 390.625;
        double c0 = exp(v0) / z, c1 = exp(v1) / z, c2 = exp(v2) / z;
        double e1 = exp(c1 - c0), e2 = exp(c2 - c0);
        double inv = 1.0 / (1.0 + e1 + e2);
        s_w[0] = (float)inv;
        s_w[1] = (float)(e1 * inv);
        s_w[2] = (float)(e2 * inv);
        s_i[0] = i0; s_i[1] = i1; s_i[2] = i2;
    }
    __syncthreads();

    if (tid < D_DIM) {
        float g0 = pool[(size_t)s_i[0] * D_DIM + tid];
        float g1 = pool[(size_t)s_i[1] * D_DIM + tid];
        float g2 = pool[(size_t)s_i[2] * D_DIM + tid];
        out_sesstopk[((size_t)row * 3 + 0) * D_DIM + tid] = g0;
        out_sesstopk[((size_t)row * 3 + 1) * D_DIM + tid] = g1;
        out_sesstopk[((size_t)row * 3 + 2) * D_DIM + tid] = g2;
        out_neighbor[(size_t)row * D_DIM + tid] =
            s_w[0] * g0 + s_w[1] * g1 + s_w[2] * g2;
        if (tid < 3) out_costopk[row * 3 + tid] = s_w[tid];
    }
}

// ---------------------------------------------------------------------------
extern "C" void kernel_launch(void* const* d_in, const int* in_sizes, int n_in,
                              void* d_out, int out_size, void* d_ws, size_t ws_size,
                              hipStream_t stream) {
    const float* sess = (const float*)d_in[0];   // [2048,128]
    const float* pool = (const float*)d_in[1];   // [100000,128]
    float* out = (float*)d_out;
    float* out_neighbor = out;
    float* out_costopk  = out + (size_t)B_ROWS * D_DIM;
    float* out_sesstopk = out_costopk + (size_t)B_ROWS * 3;

    // ws: S(512B) | S_part(400KB) | partials(3.1MB) | sess2(512KB) | pool2(25.6MB)
    float* Svec     = (float*)d_ws;
    float* S_part   = (float*)((char*)d_ws + 512);
    u64*   partials = (u64*)((char*)d_ws + 512 + (size_t)NT * 128 * 4);
    char*  sess2    = (char*)partials + (size_t)B_ROWS * NCAND * 8;
    char*  pool2    = sess2 + (size_t)B_ROWS * 256;

    pack_kernel<<<NT + 512, 256, 0, stream>>>(sess, pool, sess2, pool2, S_part);

    dim3 g3(NPC, 17);
    gemm_topk_kernel<<<g3, 256, 0, stream>>>(sess2, pool2, partials, S_part, Svec);

    finalize_kernel<<<B_ROWS, 256, 0, stream>>>(
        sess, pool, partials, Svec, out_neighbor, out_costopk, out_sesstopk);
}